// Round 5
// baseline (7259.273 us; speedup 1.0000x reference)
//
#include <hip/hip_runtime.h>
#include <math.h>

// Grid-LSTM B=128, T=256, L=2, H=512.
// Persistent cooperative kernel: 513 rounds (A: {c00(t), c11(t-1)}, B: {c01(t), c10(t)}),
// weights LDS-resident, device-wide barrier between rounds.
// v5: latency attack. 512 thr/block (8 waves/CU, 2x MLP); raw s_barrier barrier (no
// implicit vmcnt drain) so the "old" operand half of the next round is prefetched into
// registers BEFORE the barrier and stays in flight across it; H0in pre-converted to
// bf16 one timestep ahead (1 elem/thread, double-buffered). sc1 write-through stores +
// one buffer_inv sc1 per CU per round (v4 coherence scheme, proven).

static constexpr int Hn = 512;
static constexpr int Bn = 128;
static constexpr int Tn = 256;
static constexpr long THn = (long)Tn * Hn;   // 131072
static constexpr long LBH = (long)Bn * Hn;   // 65536
static constexpr int NBLK = 256;
static constexpr int NROUND = 2 * Tn + 1;    // 513

typedef __attribute__((ext_vector_type(8))) short short8;
typedef __attribute__((ext_vector_type(4))) float floatx4;

__device__ __forceinline__ unsigned short f2bf(float f) {
    unsigned u = __builtin_bit_cast(unsigned, f);
    unsigned r = u + 0x7FFFu + ((u >> 16) & 1u);   // RNE
    return (unsigned short)(r >> 16);
}
__device__ __forceinline__ unsigned pk2(float a, float b) {
    return (unsigned)f2bf(a) | ((unsigned)f2bf(b) << 16);
}
__device__ __forceinline__ float sel4(float a, float b, float cc, float d, int s) {
    float r = a;
    r = (s == 1) ? b : r;
    r = (s == 2) ? cc : r;
    r = (s == 3) ? d : r;
    return r;
}
__device__ __forceinline__ float selc(floatx4 v, int s) {
    float r = v[0];
    r = (s == 1) ? v[1] : r;
    r = (s == 2) ? v[2] : r;
    r = (s == 3) ? v[3] : r;
    return r;
}

// ---- sc1 write-through stores (device-coherent, no dirty L2 state) ----
__device__ __forceinline__ void st16_sc(unsigned short* p, unsigned short v) {
    asm volatile("global_store_short %0, %1, off sc1" :: "v"(p), "v"(v) : "memory");
}
__device__ __forceinline__ void st32_sc(float* p, float v) {
    asm volatile("global_store_dword %0, %1, off sc1" :: "v"(p), "v"(v) : "memory");
}

struct Params {
    const float* H0in;
    const float* Wih; const float* Whh;
    const float* bih; const float* bhh;
    unsigned short* h0A; unsigned short* h0B;
    unsigned short* H1b;        // [2 parity][2 layer][B][H] bf16
    unsigned short* h0inB;      // [2 parity][B][H] bf16 pre-converted input slices
    float* m0;                  // [B][H] fp32 (c00 -> c10 cell state)
    float* outH0; float* outH1; float* outM0; float* outM1;
    unsigned* bar;              // leaf[i] at bar[i*16], i=0..7; root at bar[128]
};

struct RoundDesc {
    const unsigned short* x;    // k<512 operand (fresh, cached read)
    const unsigned short* hB;   // k>=512 operand when !PF
    const float* cin;           // KIND2: m0
    unsigned short* hOutB;      // bf16 recurrent h out (sc1)
    float* coutA;               // KIND0: m0 (stride 512); KIND2: outM0+t*Hn (stride THn)
    float* hOut2;               // KIND2: outH0+t*Hn; KIND1/3: final outH1 slice (stride 1024)
    float* cOut2;               // KIND1/3 final outM1 slice
};

// Raw-barrier device-wide sync. Caller drains its sc1 stores (vmcnt(0)) and may issue
// prefetch loads BEFORE calling -- raw s_barrier does not drain vmem, so prefetches
// stay in flight across the wait. All-relaxed monotone counters; one buffer_inv sc1
// per CU (wave 0) after release makes prior rounds' sc1 writes visible to cached reads.
__device__ __forceinline__ void gridBarrierRaw(unsigned* bar, int leafIdx, unsigned target) {
    __builtin_amdgcn_s_barrier();            // all waves' stores drained before signal
    asm volatile("" ::: "memory");
    if (threadIdx.x == 0) {
        unsigned prev = __hip_atomic_fetch_add(&bar[leafIdx * 16], 1u,
                                               __ATOMIC_RELAXED, __HIP_MEMORY_SCOPE_AGENT);
        if ((prev & 31u) == 31u) {
            __hip_atomic_fetch_add(&bar[128], 1u, __ATOMIC_RELAXED, __HIP_MEMORY_SCOPE_AGENT);
        }
        while (__hip_atomic_load(&bar[128], __ATOMIC_RELAXED, __HIP_MEMORY_SCOPE_AGENT) < target) {
            __builtin_amdgcn_s_sleep(1);
        }
    }
    __builtin_amdgcn_s_barrier();
    asm volatile("" ::: "memory");
    if (threadIdx.x < 64) {     // one wave invalidates this CU's L1 + XCD L2
        asm volatile("buffer_inv sc1" ::: "memory");
        asm volatile("s_waitcnt vmcnt(0)" ::: "memory");
    }
    __builtin_amdgcn_s_barrier();
    asm volatile("" ::: "memory");
}

// Weight chunk (cell, jt) -> LDS in MFMA-fragment granule order:
// granule (ks, row, q) at byte ks*2048 + row*64 + q*16 holds B[row][k], k=ks*32+q*8..+8.
// row = jj*4+g (jj=0..7, g=0..3), K=1024 spanning [Wih | Whh]. 512 threads cooperate.
__device__ __forceinline__ void loadChunk(char* dst, const float* Wih, const float* Whh,
                                          int cell, int jt, int tid) {
    const int rw = tid >> 4;              // 0..31
    const int jj = rw >> 2, g = rw & 3;
    const long nrow = (long)cell * 2048 + (long)g * 512 + jt * 8 + jj;
    const float* baseI = Wih + nrow * 512;
    const float* baseH = Whh + nrow * 512;
    const int k0 = (tid & 15) * 64;
    #pragma unroll
    for (int i = 0; i < 8; ++i) {
        int k = k0 + i * 8;
        const float* src = (k < 512) ? (baseI + k) : (baseH + (k - 512));
        float4 v0 = *(const float4*)src;
        float4 v1 = *(const float4*)(src + 4);
        uint4 w = {pk2(v0.x, v0.y), pk2(v0.z, v0.w), pk2(v1.x, v1.y), pk2(v1.z, v1.w)};
        int byteOff = (k >> 5) * 2048 + rw * 64 + ((k >> 3) & 3) * 16;
        *(uint4*)(dst + byteOff) = w;
    }
}

// One cell round, per-wave 16x16 output tile. K=1024: ks 0..15 = x-half (fresh loads),
// ks 16..31 = h-half (PF ? prefetched regs : fresh loads). Fused LSTM epilogue.
// KIND: 0=c00 (cin=0, cout->m0), 1=c01 (reg cstate), 2=c10 (cin=m0, outputs), 3=c11 (reg).
template<int KIND, bool PF>
__device__ __forceinline__ void runCell(const RoundDesc& D, const char* chunk,
                                        const float bias[4], long arow, int outRow,
                                        int jglob, int c, int q, int cg,
                                        float& cst, const short8 pfr[16]) {
    short8 xfr[16];
    #pragma unroll
    for (int ks = 0; ks < 16; ++ks)
        xfr[ks] = *(const short8*)(D.x + arow * 512 + ks * 32 + q * 8);
    short8 hfr[16];
    if constexpr (!PF) {
        #pragma unroll
        for (int ks = 0; ks < 16; ++ks)
            hfr[ks] = *(const short8*)(D.hB + arow * 512 + ks * 32 + q * 8);
    }
    float cin = 0.f;
    if constexpr (KIND == 2)
        cin = D.cin[(long)outRow * 512 + jglob];

    floatx4 acc = {0.f, 0.f, 0.f, 0.f};
    const char* base = chunk + ((cg * 16 + c) * 64 + q * 16);
    #pragma unroll
    for (int ks = 0; ks < 16; ++ks) {
        short8 b = *(const short8*)(base + ks * 2048);
        acc = __builtin_amdgcn_mfma_f32_16x16x32_bf16(xfr[ks], b, acc, 0, 0, 0);
    }
    #pragma unroll
    for (int ks = 0; ks < 16; ++ks) {
        short8 b = *(const short8*)(base + (16 + ks) * 2048);
        const short8 a = PF ? pfr[ks] : hfr[ks];
        acc = __builtin_amdgcn_mfma_f32_16x16x32_bf16(a, b, acc, 0, 0, 0);
    }

    // gate gather within each lane-quad; lane owns (outRow, jglob)
    const int g = c & 3;
    float s0 = selc(acc, g);
    float s1 = __shfl_xor(selc(acc, g ^ 1), 1);
    float s2 = __shfl_xor(selc(acc, g ^ 2), 2);
    float s3 = __shfl_xor(selc(acc, g ^ 3), 3);
    float iv = sel4(s0, s1, s2, s3, g)     + bias[0];
    float fv = sel4(s0, s1, s2, s3, g ^ 1) + bias[1];
    float gv = sel4(s0, s1, s2, s3, g ^ 2) + bias[2];
    float ov = sel4(s0, s1, s2, s3, g ^ 3) + bias[3];

    float cold;
    if constexpr (KIND == 0)      cold = 0.f;
    else if constexpr (KIND == 2) cold = cin;
    else                          cold = cst;
    float si = 1.f / (1.f + expf(-iv));
    float sf = 1.f / (1.f + expf(-fv));
    float so = 1.f / (1.f + expf(-ov));
    float cn = sf * cold + si * tanhf(gv);
    float hn = so * tanhf(cn);

    st16_sc(D.hOutB + (long)outRow * 512 + jglob, f2bf(hn));
    if constexpr (KIND == 0)
        st32_sc(D.coutA + (long)outRow * 512 + jglob, cn);
    if constexpr (KIND == 2) {
        st32_sc(D.coutA + (long)outRow * THn + jglob, cn);
        st32_sc(D.hOut2 + (long)outRow * THn + jglob, hn);
    }
    if constexpr (KIND == 1 || KIND == 3) {
        cst = cn;
        if (D.hOut2) {
            st32_sc(D.hOut2 + (long)outRow * 1024 + jglob, hn);
            st32_sc(D.cOut2 + (long)outRow * 1024 + jglob, cn);
        }
    }
}

__global__ __launch_bounds__(512, 2) void grid_lstm_persist(Params P) {
    __shared__ char smem[2 * 65536];   // [A-role chunk][B-role chunk]

    const int tid = threadIdx.x;
    const int lane = tid & 63;
    const int wid = tid >> 6;          // 0..7
    const int c = lane & 15;
    const int q = lane >> 4;
    const int rg = wid & 3;            // row-group (16 rows)
    const int cg = wid >> 2;           // col-group (16 MFMA cols)
    const int blk = blockIdx.x;
    const int pair = blk >> 1;
    const int half = blk & 1;          // rows [half*64, half*64+64)
    const int jt = pair & 63;
    const bool hiPair = pair >= 64;
    const int cellA = hiPair ? 3 : 0;  // c11 : c00
    const int cellB = hiPair ? 2 : 1;  // c10 : c01
    const int leafIdx = blk & 7;

    loadChunk(smem,         P.Wih, P.Whh, cellA, jt, tid);
    loadChunk(smem + 65536, P.Wih, P.Whh, cellB, jt, tid);

    const int row0 = half * 64 + rg * 16;
    const long arow = row0 + c;
    const int jglob = jt * 8 + cg * 4 + (c >> 2);
    const int outRow = row0 + q * 4 + (c & 3);

    float biasA[4], biasB[4];
    #pragma unroll
    for (int g2 = 0; g2 < 4; ++g2) {
        long ia = (long)cellA * 2048 + (long)g2 * 512 + jglob;
        long ib = (long)cellB * 2048 + (long)g2 * 512 + jglob;
        biasA[g2] = P.bih[ia] + P.bhh[ia];
        biasB[g2] = P.bih[ib] + P.bhh[ib];
    }

    // prologue: convert H0in slice 0 -> bf16 (1 elem per thread for tid<256)
    if (tid < 256) {
        int idx = blk * 256 + tid;
        float hv = P.H0in[(long)(idx >> 9) * THn + (idx & 511)];
        st16_sc(P.h0inB + idx, f2bf(hv));
    }
    __syncthreads();
    asm volatile("s_waitcnt vmcnt(0)" ::: "memory");
    unsigned bnum = 1;
    gridBarrierRaw(P.bar, leafIdx, 8u * bnum); ++bnum;

    float cst = 0.f;                   // block-private layer cell state (c01 / c11)
    short8 pfr[16];

    for (int r = 0; r < NROUND; ++r) {
        const int t = r >> 1;
        const bool stB = (r & 1) != 0;

        // input pre-conversion for slice t+1 (A-rounds): issue load early, store late
        const bool doConv = (!stB) && (t + 1 < Tn) && (tid < 256);
        float convV = 0.f; int convIdx = 0;
        if (doConv) {
            convIdx = blk * 256 + tid;
            convV = P.H0in[(long)(convIdx >> 9) * THn + (long)(t + 1) * Hn + (convIdx & 511)];
        }

        if (!stB) {
            if (!hiPair) {                      // c00(t)
                if (t < Tn) {
                    int p = t & 1;
                    RoundDesc D{};
                    D.x = P.H1b + ((long)p * 2 + 0) * LBH;
                    D.hB = P.h0inB + (long)(t & 1) * LBH;
                    D.hOutB = P.h0A;
                    D.coutA = P.m0;
                    if (r == 0) runCell<0, false>(D, smem, biasA, arow, outRow, jglob, c, q, cg, cst, pfr);
                    else        runCell<0, true >(D, smem, biasA, arow, outRow, jglob, c, q, cg, cst, pfr);
                }
            } else {                            // c11(t-1)
                int tc = t - 1;
                if (tc >= 0) {
                    int p = tc & 1;
                    RoundDesc D{};
                    D.x = P.h0B;
                    D.hOutB = P.H1b + ((long)(1 - p) * 2 + 1) * LBH;
                    if (tc == Tn - 1) {
                        D.hOut2 = P.outH1 + Hn;
                        D.cOut2 = P.outM1 + Hn;
                    }
                    runCell<3, true>(D, smem, biasA, arow, outRow, jglob, c, q, cg, cst, pfr);
                }
            }
        } else {
            int p = t & 1;
            if (!hiPair) {                      // c01(t)
                RoundDesc D{};
                D.x = P.h0A;
                D.hOutB = P.H1b + ((long)(1 - p) * 2 + 0) * LBH;
                if (t == Tn - 1) {
                    D.hOut2 = P.outH1;
                    D.cOut2 = P.outM1;
                }
                runCell<1, true>(D, smem + 65536, biasB, arow, outRow, jglob, c, q, cg, cst, pfr);
            } else {                            // c10(t): both halves fresh (no prefetch)
                RoundDesc D{};
                D.x = P.H1b + ((long)p * 2 + 1) * LBH;
                D.hB = P.h0A;
                D.cin = P.m0;
                D.hOutB = P.h0B;
                D.coutA = P.outM0 + (long)t * Hn;
                D.hOut2 = P.outH0 + (long)t * Hn;
                runCell<2, false>(D, smem + 65536, biasB, arow, outRow, jglob, c, q, cg, cst, pfr);
            }
        }

        if (doConv)
            st16_sc(P.h0inB + (long)((t + 1) & 1) * LBH + convIdx, f2bf(convV));

        if (r + 1 < NROUND) {
            // drain this round's sc1 stores, THEN issue next round's h-half prefetch:
            // the loads stay in flight across the raw-barrier wait.
            asm volatile("s_waitcnt vmcnt(0)" ::: "memory");
            const unsigned short* hp = nullptr;
            if (!hiPair) {
                if (((r + 1) & 1) != 0) {       // next B: c01(t) reads H1b[t&1][0] (written r-2)
                    hp = P.H1b + ((long)(t & 1) * 2 + 0) * LBH;
                } else if (t + 1 < Tn) {        // next A: c00(t+1) reads h0inB slice t+1 (written r-1)
                    hp = P.h0inB + (long)((t + 1) & 1) * LBH;
                }
            } else {
                if (((r + 1) & 1) == 0) {       // next A: c11(tcn) reads H1b[tcn&1][1] (written r-1)
                    int tcn = ((r + 1) >> 1) - 1;
                    hp = P.H1b + ((long)(tcn & 1) * 2 + 1) * LBH;
                }
            }
            if (hp) {
                #pragma unroll
                for (int ks = 0; ks < 16; ++ks)
                    pfr[ks] = *(const short8*)(hp + arow * 512 + ks * 32 + q * 8);
            }
            gridBarrierRaw(P.bar, leafIdx, 8u * bnum); ++bnum;
        }
    }
}

extern "C" void kernel_launch(void* const* d_in, const int* in_sizes, int n_in,
                              void* d_out, int out_size, void* d_ws, size_t ws_size,
                              hipStream_t stream) {
    (void)in_sizes; (void)n_in; (void)out_size; (void)ws_size;
    const float* H0in = (const float*)d_in[0];
    const float* Wih  = (const float*)d_in[1];
    const float* Whh  = (const float*)d_in[2];
    const float* bih  = (const float*)d_in[3];
    const float* bhh  = (const float*)d_in[4];
    float* out = (float*)d_out;

    // workspace (~1.6 MB): bf16 state bufs + fp32 m0 + barrier + bf16 input slices
    unsigned short* h0A = (unsigned short*)d_ws;
    unsigned short* h0B = h0A + LBH;
    unsigned short* H1b = h0B + LBH;                  // [2][2][B][H] bf16
    float* m0 = (float*)(H1b + 4 * LBH);              // [B][H] fp32
    unsigned* bar = (unsigned*)(m0 + LBH);            // leaf[8]@stride16 + root@128
    unsigned short* h0inB = (unsigned short*)(bar + 256);  // [2][B][H] bf16 (not zeroed)

    size_t zeroBytes = (size_t)((char*)(bar + 256) - (char*)d_ws);
    hipMemsetAsync(d_ws, 0, zeroBytes, stream);

    Params P;
    P.H0in = H0in; P.Wih = Wih; P.Whh = Whh; P.bih = bih; P.bhh = bhh;
    P.h0A = h0A; P.h0B = h0B; P.H1b = H1b; P.h0inB = h0inB; P.m0 = m0;
    P.outH0 = out;
    P.outH1 = out + (long)Bn * THn;
    P.outM0 = P.outH1 + 2 * LBH;
    P.outM1 = P.outM0 + (long)Bn * THn;
    P.bar = bar;

    void* args[] = {&P};
    hipLaunchCooperativeKernel((void*)grid_lstm_persist, dim3(NBLK), dim3(512),
                               args, 0, stream);
}

// Round 6
// 5928.746 us; speedup vs baseline: 1.2244x; 1.2244x over previous
//
#include <hip/hip_runtime.h>
#include <math.h>

// Grid-LSTM B=128, T=256, L=2, H=512.
// Persistent cooperative kernel: 513 rounds (A: {c00(t), c11(t-1)}, B: {c01(t), c10(t)}),
// weights LDS-resident, device-wide barrier between rounds.
// v6 = v4 shape (256 thr, 4 waves, 2 accs/wave) with the read protocol changed:
// cross-block state reads are agent-scope relaxed atomic loads (L2-bypass, served at
// the IF$ coherence point) -> the per-round buffer_inv is GONE. Steady state has zero
// cache-maintenance instructions. Stores remain sc1 write-through (proven v4 chain).
// Read-only inputs (H0in, weights, biases) remain plain cached - and L2 now persists.

static constexpr int Hn = 512;
static constexpr int Bn = 128;
static constexpr int Tn = 256;
static constexpr long THn = (long)Tn * Hn;   // 131072
static constexpr long LBH = (long)Bn * Hn;   // 65536
static constexpr int NBLK = 256;
static constexpr int NROUND = 2 * Tn + 1;    // 513

typedef __attribute__((ext_vector_type(8))) short short8;
typedef __attribute__((ext_vector_type(4))) float floatx4;

__device__ __forceinline__ unsigned short f2bf(float f) {
    unsigned u = __builtin_bit_cast(unsigned, f);
    unsigned r = u + 0x7FFFu + ((u >> 16) & 1u);   // RNE
    return (unsigned short)(r >> 16);
}
__device__ __forceinline__ unsigned pk2(float a, float b) {
    return (unsigned)f2bf(a) | ((unsigned)f2bf(b) << 16);
}
__device__ __forceinline__ float sel4(float a, float b, float cc, float d, int s) {
    float r = a;
    r = (s == 1) ? b : r;
    r = (s == 2) ? cc : r;
    r = (s == 3) ? d : r;
    return r;
}
__device__ __forceinline__ float selc(floatx4 v, int s) {
    float r = v[0];
    r = (s == 1) ? v[1] : r;
    r = (s == 2) ? v[2] : r;
    r = (s == 3) ? v[3] : r;
    return r;
}

// ---- coherent (agent-scope) state access ----
// Loads: relaxed atomic 8B granules -> compiler-emitted L2-bypass loads, correct
// register management (no inline-asm in-flight hazard), freely pipelined.
__device__ __forceinline__ short8 ald_frag(const unsigned short* p) {
    union { unsigned long long d[2]; short8 s; } u;
    u.d[0] = __hip_atomic_load((const unsigned long long*)p, __ATOMIC_RELAXED,
                               __HIP_MEMORY_SCOPE_AGENT);
    u.d[1] = __hip_atomic_load((const unsigned long long*)p + 1, __ATOMIC_RELAXED,
                               __HIP_MEMORY_SCOPE_AGENT);
    return u.s;
}
__device__ __forceinline__ float ald_f32(const float* p) {
    return __hip_atomic_load(p, __ATOMIC_RELAXED, __HIP_MEMORY_SCOPE_AGENT);
}
// Stores: sc1 write-through (no dirty L2 state; acked at coherence point).
__device__ __forceinline__ void st16_sc(unsigned short* p, unsigned short v) {
    asm volatile("global_store_short %0, %1, off sc1" :: "v"(p), "v"(v) : "memory");
}
__device__ __forceinline__ void st32_sc(float* p, float v) {
    asm volatile("global_store_dword %0, %1, off sc1" :: "v"(p), "v"(v) : "memory");
}

struct Params {
    const float* H0in;
    const float* Wih; const float* Whh;
    const float* bih; const float* bhh;
    unsigned short* h0A; unsigned short* h0B;
    unsigned short* H1b;        // [2 parity][2 layer][B][H] bf16
    float* m0;                  // [B][H] fp32 (c00 -> c10 cell state, per timestep)
    float* outH0; float* outH1; float* outM0; float* outM1;
    unsigned* bar;              // leaf[i] at bar[i*16], i=0..7; root at bar[128]
};

struct RoundDesc {
    const unsigned short* x;    // k<512 operand, bf16 state (coherent read)
    const unsigned short* hB;   // k>=512 operand, bf16 state (coherent read)
    const float* hF;            // k>=512 operand fp32 (c00: H0in slice, plain cached)
    const float* cin;           // KIND2: m0 (coherent read)
    unsigned short* hOutB;      // bf16 recurrent h out (sc1)
    float* coutA;               // KIND0: m0 (sc1). KIND2: outM0+t*Hn (sc1, stride THn)
    long cAs;
    float* hOut2;               // KIND2: outH0+t*Hn; KIND1/3: final outH1 slice (stride 1024)
    float* cOut2;               // KIND1/3 final outM1 slice
};

// Two-level device barrier, all-relaxed monotone counters. Release = per-wave
// vmcnt(0) drain (inside __syncthreads) before the leaf atomic: all sc1 stores are
// acked at the coherence point before this block signals. Acquire = nothing needed:
// subsequent state reads are agent-scope loads served at the same coherence point.
__device__ __forceinline__ void gridBarrier(unsigned* bar, int leafIdx, unsigned r) {
    asm volatile("s_waitcnt vmcnt(0)" ::: "memory");   // sc1 stores acked
    __syncthreads();
    if (threadIdx.x == 0) {
        unsigned prev = __hip_atomic_fetch_add(&bar[leafIdx * 16], 1u,
                                               __ATOMIC_RELAXED, __HIP_MEMORY_SCOPE_AGENT);
        if ((prev & 31u) == 31u) {
            __hip_atomic_fetch_add(&bar[128], 1u, __ATOMIC_RELAXED, __HIP_MEMORY_SCOPE_AGENT);
        }
        const unsigned target = 8u * (r + 1u);
        while (__hip_atomic_load(&bar[128], __ATOMIC_RELAXED, __HIP_MEMORY_SCOPE_AGENT) < target) {
            __builtin_amdgcn_s_sleep(2);
        }
    }
    __syncthreads();
    asm volatile("" ::: "memory");   // no cached-in-reg state across rounds
}

// Weight chunk (cell, jt) -> LDS in MFMA-fragment granule order:
// granule (ks, row, q) at byte ks*2048 + row*64 + q*16 holds B[row][k], k=ks*32+q*8..+8.
// row = jj*4+g (jj=0..7, g=0..3), K=1024 spanning [Wih | Whh]. Plain cached loads (RO).
__device__ __forceinline__ void loadChunk(char* dst, const float* Wih, const float* Whh,
                                          int cell, int jt, int tid) {
    const int rw = tid >> 3;              // 0..31
    const int jj = rw >> 2, g = rw & 3;
    const long nrow = (long)cell * 2048 + (long)g * 512 + jt * 8 + jj;
    const float* baseI = Wih + nrow * 512;
    const float* baseH = Whh + nrow * 512;
    const int k0 = (tid & 7) * 128;
    #pragma unroll
    for (int i = 0; i < 16; ++i) {
        int k = k0 + i * 8;
        const float* src = (k < 512) ? (baseI + k) : (baseH + (k - 512));
        float4 v0 = *(const float4*)src;
        float4 v1 = *(const float4*)(src + 4);
        uint4 w = {pk2(v0.x, v0.y), pk2(v0.z, v0.w), pk2(v1.x, v1.y), pk2(v1.z, v1.w)};
        int byteOff = (k >> 5) * 2048 + rw * 64 + ((k >> 3) & 3) * 16;
        *(uint4*)(dst + byteOff) = w;
    }
}

// One cell GEMM round for this block's 64 rows: K=1024, 32 gate-cols.
// KIND: 0=c00 (h=fp32 input, cin=0, cout->m0), 1=c01 (reg cstate),
//       2=c10 (cin=m0, couts dumped), 3=c11 (reg cstate).
template<int KIND>
__device__ __forceinline__ void runCell(const RoundDesc& D, const char* chunk,
                                        const float bias[2][4], int jt, int row0,
                                        int c, int q, float cst[2]) {
    const long arow = row0 + c;
    const int g = c & 3;
    const int cu = c >> 2;

    // ---- A-frags: coherent loads for state, plain cached for H0in ----
    short8 afr[32];
    #pragma unroll
    for (int ks = 0; ks < 16; ++ks)
        afr[ks] = ald_frag(D.x + arow * 512 + ks * 32 + q * 8);
    if constexpr (KIND == 0) {
        #pragma unroll
        for (int ks = 0; ks < 16; ++ks) {
            const float* hp = D.hF + arow * THn + ks * 32 + q * 8;
            float4 v0 = *(const float4*)(hp);
            float4 v1 = *(const float4*)(hp + 4);
            uint4 w = {pk2(v0.x, v0.y), pk2(v0.z, v0.w),
                       pk2(v1.x, v1.y), pk2(v1.z, v1.w)};
            afr[16 + ks] = __builtin_bit_cast(short8, w);
        }
    } else {
        #pragma unroll
        for (int ks = 0; ks < 16; ++ks)
            afr[16 + ks] = ald_frag(D.hB + arow * 512 + ks * 32 + q * 8);
    }
    float cin0 = 0.f, cin1 = 0.f;
    if constexpr (KIND == 2) {
        const int row = row0 + q * 4 + g;
        cin0 = ald_f32(D.cin + (long)row * 512 + jt * 8 + cu);
        cin1 = ald_f32(D.cin + (long)row * 512 + jt * 8 + 4 + cu);
    }

    // ---- K loop: B-frags from LDS (contiguous 1024B per wave-fragment) ----
    floatx4 acc0 = {0.f, 0.f, 0.f, 0.f};
    floatx4 acc1 = {0.f, 0.f, 0.f, 0.f};
    const char* base = chunk + (c * 64 + q * 16);
    #pragma unroll
    for (int ks = 0; ks < 32; ++ks) {
        short8 b0 = *(const short8*)(base + ks * 2048);
        short8 b1 = *(const short8*)(base + ks * 2048 + 1024);
        acc0 = __builtin_amdgcn_mfma_f32_16x16x32_bf16(afr[ks], b0, acc0, 0, 0, 0);
        acc1 = __builtin_amdgcn_mfma_f32_16x16x32_bf16(afr[ks], b1, acc1, 0, 0, 0);
    }

    // ---- fused epilogue: gather 4 gates within each lane-quad; lane owns row q*4+g ----
    #pragma unroll
    for (int nf = 0; nf < 2; ++nf) {
        floatx4 acc = nf ? acc1 : acc0;
        float s0 = selc(acc, g);
        float s1 = __shfl_xor(selc(acc, g ^ 1), 1);
        float s2 = __shfl_xor(selc(acc, g ^ 2), 2);
        float s3 = __shfl_xor(selc(acc, g ^ 3), 3);
        float iv = sel4(s0, s1, s2, s3, g)     + bias[nf][0];
        float fv = sel4(s0, s1, s2, s3, g ^ 1) + bias[nf][1];
        float gv = sel4(s0, s1, s2, s3, g ^ 2) + bias[nf][2];
        float ov = sel4(s0, s1, s2, s3, g ^ 3) + bias[nf][3];

        const int row = row0 + q * 4 + g;
        const int jglob = jt * 8 + nf * 4 + cu;
        float cold;
        if constexpr (KIND == 0)      cold = 0.f;
        else if constexpr (KIND == 2) cold = nf ? cin1 : cin0;
        else                          cold = cst[nf];
        float si = 1.f / (1.f + expf(-iv));
        float sf = 1.f / (1.f + expf(-fv));
        float so = 1.f / (1.f + expf(-ov));
        float cn = sf * cold + si * tanhf(gv);
        float hn = so * tanhf(cn);

        st16_sc(D.hOutB + (long)row * 512 + jglob, f2bf(hn));
        if constexpr (KIND == 0 || KIND == 2) {
            st32_sc(D.coutA + (long)row * D.cAs + jglob, cn);
        }
        if constexpr (KIND == 2) {
            st32_sc(D.hOut2 + (long)row * THn + jglob, hn);
        }
        if constexpr (KIND == 1 || KIND == 3) {
            cst[nf] = cn;
            if (D.hOut2) {
                st32_sc(D.hOut2 + (long)row * 1024 + jglob, hn);
                st32_sc(D.cOut2 + (long)row * 1024 + jglob, cn);
            }
        }
    }
}

__global__ __launch_bounds__(256, 1) void grid_lstm_persist(Params P) {
    __shared__ char smem[2 * 65536];   // [A-role chunk][B-role chunk]

    const int tid = threadIdx.x;
    const int lane = tid & 63;
    const int wid = tid >> 6;
    const int c = lane & 15;
    const int q = lane >> 4;
    const int blk = blockIdx.x;
    const int pair = blk >> 1;
    const int half = blk & 1;          // rows [half*64, half*64+64)
    const int jt = pair & 63;
    const bool hiPair = pair >= 64;
    const int cellA = hiPair ? 3 : 0;  // c11 : c00
    const int cellB = hiPair ? 2 : 1;  // c10 : c01
    const int leafIdx = blk & 7;

    // ---- prologue: weights fp32 -> bf16 -> LDS (once), biases -> registers ----
    loadChunk(smem,         P.Wih, P.Whh, cellA, jt, tid);
    loadChunk(smem + 65536, P.Wih, P.Whh, cellB, jt, tid);

    float biasA[2][4], biasB[2][4];
    {
        const int cuu = c >> 2;
        #pragma unroll
        for (int nf = 0; nf < 2; ++nf) {
            int j = jt * 8 + nf * 4 + cuu;
            #pragma unroll
            for (int g2 = 0; g2 < 4; ++g2) {
                long ia = (long)cellA * 2048 + (long)g2 * 512 + j;
                long ib = (long)cellB * 2048 + (long)g2 * 512 + j;
                biasA[nf][g2] = P.bih[ia] + P.bhh[ia];
                biasB[nf][g2] = P.bih[ib] + P.bhh[ib];
            }
        }
    }
    __syncthreads();

    const int row0 = half * 64 + wid * 16;
    float cst[2] = {0.f, 0.f};         // block-private layer cell state (c01 / c11)
    float cstDummy[2] = {0.f, 0.f};

    for (int r = 0; r < NROUND; ++r) {
        const int t = r >> 1;
        const bool stB = (r & 1) != 0;

        if (!stB) {
            if (!hiPair) {                      // c00(t): x=H1[p][0], h=H0in[t] fp32
                if (t < Tn) {
                    int p = t & 1;
                    RoundDesc D{};
                    D.x = P.H1b + ((long)p * 2 + 0) * LBH;
                    D.hF = P.H0in + (long)t * Hn;
                    D.hOutB = P.h0A;
                    D.coutA = P.m0; D.cAs = 512;
                    runCell<0>(D, smem, biasA, jt, row0, c, q, cstDummy);
                }
            } else {                            // c11(t-1)
                int tc = t - 1;
                if (tc >= 0) {
                    int p = tc & 1;
                    RoundDesc D{};
                    D.x = P.h0B;
                    D.hB = P.H1b + ((long)p * 2 + 1) * LBH;
                    D.hOutB = P.H1b + ((long)(1 - p) * 2 + 1) * LBH;
                    if (tc == Tn - 1) {
                        D.hOut2 = P.outH1 + Hn;
                        D.cOut2 = P.outM1 + Hn;
                    }
                    runCell<3>(D, smem, biasA, jt, row0, c, q, cst);
                }
            }
        } else {
            int p = t & 1;
            if (!hiPair) {                      // c01(t): x=h0A, h=H1[p][0]
                RoundDesc D{};
                D.x = P.h0A;
                D.hB = P.H1b + ((long)p * 2 + 0) * LBH;
                D.hOutB = P.H1b + ((long)(1 - p) * 2 + 0) * LBH;
                if (t == Tn - 1) {
                    D.hOut2 = P.outH1;
                    D.cOut2 = P.outM1;
                }
                runCell<1>(D, smem + 65536, biasB, jt, row0, c, q, cst);
            } else {                            // c10(t): x=H1[p][1], h=h0A
                RoundDesc D{};
                D.x = P.H1b + ((long)p * 2 + 1) * LBH;
                D.hB = P.h0A;
                D.cin = P.m0;
                D.hOutB = P.h0B;
                D.coutA = P.outM0 + (long)t * Hn; D.cAs = THn;
                D.hOut2 = P.outH0 + (long)t * Hn;
                runCell<2>(D, smem + 65536, biasB, jt, row0, c, q, cstDummy);
            }
        }
        if (r + 1 < NROUND) gridBarrier(P.bar, leafIdx, (unsigned)r);
    }
}

extern "C" void kernel_launch(void* const* d_in, const int* in_sizes, int n_in,
                              void* d_out, int out_size, void* d_ws, size_t ws_size,
                              hipStream_t stream) {
    (void)in_sizes; (void)n_in; (void)out_size; (void)ws_size;
    const float* H0in = (const float*)d_in[0];
    const float* Wih  = (const float*)d_in[1];
    const float* Whh  = (const float*)d_in[2];
    const float* bih  = (const float*)d_in[3];
    const float* bhh  = (const float*)d_in[4];
    float* out = (float*)d_out;

    // workspace: bf16 recurrent bufs + fp32 m0 + barrier counters (~1.1 MB)
    unsigned short* h0A = (unsigned short*)d_ws;
    unsigned short* h0B = h0A + LBH;
    unsigned short* H1b = h0B + LBH;                  // [2][2][B][H] bf16
    float* m0 = (float*)(H1b + 4 * LBH);              // [B][H] fp32
    unsigned* bar = (unsigned*)(m0 + LBH);            // leaf[8]@stride16 + root@128

    size_t zeroBytes = (size_t)((char*)(bar + 256) - (char*)d_ws);
    hipMemsetAsync(d_ws, 0, zeroBytes, stream);

    Params P;
    P.H0in = H0in; P.Wih = Wih; P.Whh = Whh; P.bih = bih; P.bhh = bhh;
    P.h0A = h0A; P.h0B = h0B; P.H1b = H1b; P.m0 = m0;
    P.outH0 = out;
    P.outH1 = out + (long)Bn * THn;
    P.outM0 = P.outH1 + 2 * LBH;
    P.outM1 = P.outM0 + (long)Bn * THn;
    P.bar = bar;

    void* args[] = {&P};
    hipLaunchCooperativeKernel((void*)grid_lstm_persist, dim3(NBLK), dim3(256),
                               args, 0, stream);
}